// Round 2
// baseline (449.298 us; speedup 1.0000x reference)
//
#include <hip/hip_runtime.h>
#include <hip/hip_cooperative_groups.h>

namespace cg = cooperative_groups;

// HoloGraphBlockV7 — round 11: revert GEMM tiles to R9 (BM=64/32; R10's bigger
// tiles regressed via occupancy/tail). NEW: gates+logcum+scan1+scan2+scan3
// fused into ONE cooperative kernel (512 blocks = 2/CU co-resident):
//  - RP (8MB round-trip) eliminated — local readout r stays in LDS
//  - QB loaded/staged once instead of twice
//  - phase2's serial dependent-load chain software-pipelined
//  - 3 dispatch boundaries removed (11 -> 8 dispatches)

typedef unsigned short u16;
typedef unsigned int u32;
typedef __attribute__((ext_vector_type(8))) short short8;
typedef __attribute__((ext_vector_type(4))) float floatx4;

__device__ __forceinline__ float b2f(u16 u) {
  u32 x = ((u32)u) << 16;
  return __uint_as_float(x);
}
__device__ __forceinline__ u16 f2b(float f) {
  u32 x = __float_as_uint(f);
  u32 r = (x + 0x7fffu + ((x >> 16) & 1u)) >> 16;
  return (u16)r;
}
__device__ __forceinline__ float4 b4_to_f4(uint2 u) {
  float4 r;
  r.x = __uint_as_float((u.x & 0xffffu) << 16);
  r.y = __uint_as_float(u.x & 0xffff0000u);
  r.z = __uint_as_float((u.y & 0xffffu) << 16);
  r.w = __uint_as_float(u.y & 0xffff0000u);
  return r;
}

__device__ __forceinline__ void stage16(const u16* g, u16* lds_wave_base) {
  __builtin_amdgcn_global_load_lds((const __attribute__((address_space(1))) void*)g,
                                   (__attribute__((address_space(3))) void*)lds_wave_base,
                                   16, 0, 0);
}

// Stage a ROWSx64 bf16 tile (64-wide k-block kb) into LDS [row][64] with
// chunk swizzle: LDS chunk slot m of row r holds global k-chunk m ^ (r&7).
template <int ROWS>
__device__ __forceinline__ void stage_tile64(const u16* __restrict__ G, int ldK, int kb,
                                             u16* lds, int tid) {
#pragma unroll
  for (int r = 0; r < ROWS / 32; ++r) {
    int slot = r * 256 + tid;
    int row = slot >> 3;
    int kwg = (slot & 7) ^ (row & 7);
    stage16(G + (size_t)row * ldK + kb * 64 + kwg * 8,
            lds + (size_t)(r * 256 + (tid >> 6) * 64) * 8);
  }
}

// ---------------------------------------------------------------------------
// LayerNorm of one 512-row; 256 threads.
__device__ __forceinline__ void ln_row(const float* __restrict__ xr,
                                       const float* __restrict__ g,
                                       const float* __restrict__ bt,
                                       u16* __restrict__ yr, int tid, float* red) {
  float x0 = xr[tid], x1 = xr[tid + 256];
  float s = x0 + x1, ss = x0 * x0 + x1 * x1;
#pragma unroll
  for (int o = 32; o > 0; o >>= 1) { s += __shfl_xor(s, o); ss += __shfl_xor(ss, o); }
  if ((tid & 63) == 0) { red[tid >> 6] = s; red[4 + (tid >> 6)] = ss; }
  __syncthreads();
  float ts = red[0] + red[1] + red[2] + red[3];
  float tss = red[4] + red[5] + red[6] + red[7];
  float mu = ts * (1.f / 512.f);
  float var = tss * (1.f / 512.f) - mu * mu;
  float rstd = 1.0f / sqrtf(var + 1e-5f);
  yr[tid] = f2b((x0 - mu) * rstd * g[tid] + bt[tid]);
  yr[tid + 256] = f2b((x1 - mu) * rstd * g[tid + 256] + bt[tid + 256]);
}

// ---------------------------------------------------------------------------
// Prep: weight transposes f32->bf16 (0..3327), gate/bias pack (3328..3391),
// LN1 rows (3392..5439).
__global__ __launch_bounds__(256) void prep_weights(
    const float* __restrict__ Wk, const float* __restrict__ Wq,
    const float* __restrict__ Wv, const float* __restrict__ Wo,
    const float* __restrict__ Wps, const float* __restrict__ W1,
    const float* __restrict__ W2, const float* __restrict__ Wd,
    const float* __restrict__ Wgw, const float* __restrict__ Wgf,
    const float* __restrict__ bk, const float* __restrict__ bq,
    const float* __restrict__ bv, const float* __restrict__ bd,
    const float* __restrict__ bgw, const float* __restrict__ bgf,
    const float* __restrict__ x, const float* __restrict__ ln1g,
    const float* __restrict__ ln1b,
    u16* __restrict__ WTQ, u16* __restrict__ WTO, u16* __restrict__ WTPS,
    u16* __restrict__ WT1, u16* __restrict__ WT2, float* __restrict__ BQV,
    u16* __restrict__ XN) {
  int bid = blockIdx.x, tid = threadIdx.x;
  __shared__ float tile[32][33];
  __shared__ float red[8];
  if (bid < 3328) {
    const float* src;
    u16* dst;
    int C, rel, tiles_x;
    if (bid < 256)       { src = Wk;  dst = WTQ;           C = 512;  rel = bid;        tiles_x = 16; }
    else if (bid < 512)  { src = Wq;  dst = WTQ + 262144;  C = 512;  rel = bid - 256;  tiles_x = 16; }
    else if (bid < 768)  { src = Wv;  dst = WTQ + 524288;  C = 512;  rel = bid - 512;  tiles_x = 16; }
    else if (bid < 1024) { src = Wo;  dst = WTO;           C = 512;  rel = bid - 768;  tiles_x = 16; }
    else if (bid < 1280) { src = Wps; dst = WTPS;          C = 512;  rel = bid - 1024; tiles_x = 16; }
    else if (bid < 2304) { src = W1;  dst = WT1;           C = 2048; rel = bid - 1280; tiles_x = 64; }
    else                 { src = W2;  dst = WT2;           C = 512;  rel = bid - 2304; tiles_x = 16; }
    int R = (bid >= 1280 && bid < 2304) ? 512 : (bid >= 2304 ? 2048 : 512);
    int c0 = (rel % tiles_x) * 32, r0 = (rel / tiles_x) * 32;
    int tx = tid & 31, ty = tid >> 5;
#pragma unroll
    for (int i = 0; i < 4; ++i)
      tile[ty + i * 8][tx] = src[(size_t)(r0 + ty + i * 8) * C + c0 + tx];
    __syncthreads();
#pragma unroll
    for (int i = 0; i < 4; ++i)
      dst[(size_t)(c0 + ty + i * 8) * R + r0 + tx] = f2b(tile[tx][ty + i * 8]);
  } else if (bid < 3392) {
    int idx = (bid - 3328) * 256 + tid;
    const int stride = 64 * 256;
    for (int i = idx; i < 128 * 512; i += stride) {
      int local = i >> 9, k = i & 511;
      float v = 0.f;
      if (local < 8) v = Wd[k * 8 + local];
      else if (local < 16) v = Wgw[k * 8 + (local - 8)];
      else if (local < 24) v = Wgf[k * 8 + (local - 16)];
      WTQ[(size_t)(1536 + local) * 512 + k] = f2b(v);
    }
    for (int i = idx; i < 1664; i += stride) {
      float v = 0.f;
      if (i < 512) v = bk[i];
      else if (i < 1024) v = bq[i - 512];
      else if (i < 1536) v = bv[i - 1024];
      else if (i < 1544) v = bd[i - 1536];
      else if (i < 1552) v = bgw[i - 1544];
      else if (i < 1560) v = bgf[i - 1552];
      BQV[i] = v;
    }
  } else {
    int row = bid - 3392;
    ln_row(x + (size_t)row * 512, ln1g, ln1b, XN + (size_t)row * 512, tid, red);
  }
}

// Standalone LN2.
__global__ __launch_bounds__(256) void ln_f32(const float* __restrict__ X,
                                              const float* __restrict__ g,
                                              const float* __restrict__ bt,
                                              u16* __restrict__ Y) {
  __shared__ float red[8];
  ln_row(X + (size_t)blockIdx.x * 512, g, bt, Y + (size_t)blockIdx.x * 512,
         threadIdx.x, red);
}

// ---------------------------------------------------------------------------
// BMx64-tile, BK=64, 2-stage LDS GEMM. 256 threads = 2x2 waves.
// BM=64: 4 blocks/CU; BM=32: 6 blocks/CU.
// EPI 1: outf = aux0+v+0.1*aux1
// EPI 2: outb = bf16(gelu(v))
// EPI 3: w = aux0+v; outf = w; outb = bf16(w)
// EPI 4: outf = aux0+v; outf2 = aux1+v
// EPI 5 (QKV, N=1664): n-tile sections: [0,512) l2norm->outb(KB);
//   [512,1024) l2norm->outb2(QB); [1024,1536) tanh->outb3(VB);
//   [1536,1664) raw f32 -> outf(G0, 2048x128).
template <int BM, int EPI>
__global__ __launch_bounds__(256, (BM == 128 ? 3 : BM == 64 ? 4 : 6)) void gemm2s(
    const u16* __restrict__ A, const u16* __restrict__ BT, const float* __restrict__ bias,
    float* __restrict__ outf, float* __restrict__ outf2, u16* __restrict__ outb,
    u16* __restrict__ outb2, u16* __restrict__ outb3,
    const float* __restrict__ aux0, const float* __restrict__ aux1, int M, int N, int K) {
  constexpr int MT = BM / 32;
  constexpr int S = BM / 32 + 2;  // DMA insts per thread per k-tile
  __shared__ __align__(16) u16 As[2][BM * 64];
  __shared__ __align__(16) u16 Bs[2][64 * 64];
  __shared__ float ssb[2][BM];
  const int tid = threadIdx.x;
  const int lane = tid & 63, wave = tid >> 6;
  const int wm = wave >> 1, wn = wave & 1;
  const int m0 = blockIdx.y * BM, n0 = blockIdx.x * 64;
  floatx4 acc[MT][2] = {};
  const int fr = lane & 15, kq = lane >> 4;
  const int nk = K >> 6;
  const u16* Ab = A + (size_t)m0 * K;
  const u16* Bb = BT + (size_t)n0 * K;

  stage_tile64<BM>(Ab, K, 0, As[0], tid);
  stage_tile64<64>(Bb, K, 0, Bs[0], tid);

  for (int kb = 0; kb < nk; ++kb) {
    const int cur = kb & 1;
    if (kb + 1 < nk) {
      stage_tile64<BM>(Ab, K, kb + 1, As[cur ^ 1], tid);
      stage_tile64<64>(Bb, K, kb + 1, Bs[cur ^ 1], tid);
      if constexpr (S == 6) asm volatile("s_waitcnt vmcnt(6)" ::: "memory");
      else if constexpr (S == 4) asm volatile("s_waitcnt vmcnt(4)" ::: "memory");
      else asm volatile("s_waitcnt vmcnt(3)" ::: "memory");
    } else {
      asm volatile("s_waitcnt vmcnt(0)" ::: "memory");
    }
    asm volatile("s_barrier" ::: "memory");

#pragma unroll
    for (int sub = 0; sub < 2; ++sub) {
      short8 af[MT], bf[2];
#pragma unroll
      for (int mt = 0; mt < MT; ++mt) {
        int row = wm * (BM / 2) + mt * 16 + fr;
        int c = sub * 4 + kq;
        af[mt] = *(const short8*)&As[cur][row * 64 + ((c ^ (row & 7)) << 3)];
      }
#pragma unroll
      for (int nt = 0; nt < 2; ++nt) {
        int row = wn * 32 + nt * 16 + fr;
        int c = sub * 4 + kq;
        bf[nt] = *(const short8*)&Bs[cur][row * 64 + ((c ^ (row & 7)) << 3)];
      }
#pragma unroll
      for (int mt = 0; mt < MT; ++mt)
#pragma unroll
        for (int nt = 0; nt < 2; ++nt)
          acc[mt][nt] =
              __builtin_amdgcn_mfma_f32_16x16x32_bf16(af[mt], bf[nt], acc[mt][nt], 0, 0, 0);
    }
    asm volatile("s_waitcnt lgkmcnt(0)" ::: "memory");
    asm volatile("s_barrier" ::: "memory");
  }

  const int col = lane & 15;
  const int rbase = (lane >> 4) * 4;

  // v (acc + bias), per (mt, nt, r)
  float vv[MT][2][4];
#pragma unroll
  for (int nt = 0; nt < 2; ++nt) {
    int gc = n0 + wn * 32 + nt * 16 + col;
    float bvv = bias[gc];
#pragma unroll
    for (int mt = 0; mt < MT; ++mt)
#pragma unroll
      for (int r = 0; r < 4; ++r) vv[mt][nt][r] = acc[mt][nt][r] + bvv;
  }

  if constexpr (EPI == 5) {
    const int sec = n0 >> 9;              // 0 K, 1 Q, 2 V, 3 gates
    const int h = (n0 & 511) >> 6;        // head (BN=64 == head size)
    if (sec == 3) {
#pragma unroll
      for (int nt = 0; nt < 2; ++nt) {
        int gcl = (n0 - 1536) + wn * 32 + nt * 16 + col;
#pragma unroll
        for (int mt = 0; mt < MT; ++mt) {
          int gr = m0 + wm * (BM / 2) + mt * 16 + rbase;
#pragma unroll
          for (int r = 0; r < 4; ++r)
            outf[(size_t)(gr + r) * 128 + gcl] = vv[mt][nt][r];
        }
      }
    } else if (sec == 2) {
#pragma unroll
      for (int nt = 0; nt < 2; ++nt) {
        int d = wn * 32 + nt * 16 + col;
#pragma unroll
        for (int mt = 0; mt < MT; ++mt) {
          int gr = m0 + wm * (BM / 2) + mt * 16 + rbase;
#pragma unroll
          for (int r = 0; r < 4; ++r) {
            int tok = gr + r;
            int bh = (tok >> 10) * 8 + h;
            outb3[((size_t)bh * 1024 + (tok & 1023)) * 64 + d] = f2b(tanhf(vv[mt][nt][r]));
          }
        }
      }
    } else {
      // l2norm over the head's 64 cols: wave-local 32-col sum + LDS exchange.
#pragma unroll
      for (int mt = 0; mt < MT; ++mt) {
#pragma unroll
        for (int r = 0; r < 4; ++r) {
          float ss = vv[mt][0][r] * vv[mt][0][r] + vv[mt][1][r] * vv[mt][1][r];
          ss += __shfl_xor(ss, 1);
          ss += __shfl_xor(ss, 2);
          ss += __shfl_xor(ss, 4);
          ss += __shfl_xor(ss, 8);
          if ((lane & 15) == 0)
            ssb[wn][wm * (BM / 2) + mt * 16 + rbase + r] = ss;
        }
      }
      __syncthreads();
      u16* dst = (sec == 0) ? outb : outb2;
#pragma unroll
      for (int mt = 0; mt < MT; ++mt) {
#pragma unroll
        for (int r = 0; r < 4; ++r) {
          int br = wm * (BM / 2) + mt * 16 + rbase + r;
          float tot = ssb[0][br] + ssb[1][br];
          float rs = 1.0f / fmaxf(sqrtf(tot), 1e-12f);
          int tok = m0 + br;
          int bh = (tok >> 10) * 8 + h;
          size_t base = ((size_t)bh * 1024 + (tok & 1023)) * 64;
#pragma unroll
          for (int nt = 0; nt < 2; ++nt) {
            int d = wn * 32 + nt * 16 + col;
            dst[base + d] = f2b(vv[mt][nt][r] * rs);
          }
        }
      }
    }
  } else {
#pragma unroll
    for (int nt = 0; nt < 2; ++nt) {
      int gc = n0 + wn * 32 + nt * 16 + col;
#pragma unroll
      for (int mt = 0; mt < MT; ++mt) {
        int gr = m0 + wm * (BM / 2) + mt * 16 + rbase;
#pragma unroll
        for (int r = 0; r < 4; ++r) {
          size_t idx = (size_t)(gr + r) * N + gc;
          float v = vv[mt][nt][r];
          if constexpr (EPI == 1) {
            outf[idx] = aux0[idx] + v + 0.1f * aux1[idx];
          } else if constexpr (EPI == 2) {
            outb[idx] = f2b(0.5f * v * (1.f + erff(v * 0.70710678118654752f)));
          } else if constexpr (EPI == 3) {
            float w = aux0[idx] + v;
            outf[idx] = w;
            outb[idx] = f2b(w);
          } else if constexpr (EPI == 4) {
            outf[idx] = aux0[idx] + v;
            outf2[idx] = aux1[idx] + v;
          }
        }
      }
    }
  }
}

// ---------------------------------------------------------------------------
// Fused scan: gates+logcum (phase0) -> local chunk scan (phase1) ->
// cross-chunk combine (phase2) -> inter-chunk add + bf16 readout (phase3).
// Cooperative launch, grid (32,8,2) = 512 blocks = 2/CU co-resident.
// RP lives in LDS (sv rows, overwritten after last read — same-wave ordering);
// Q tile staged once and reused by phase3.
__global__ __launch_bounds__(256, 2) void scan_fused(
    const u16* __restrict__ KB, const u16* __restrict__ QB, const u16* __restrict__ VB,
    const float* __restrict__ G0, float* __restrict__ DEC, float* __restrict__ WS,
    float* __restrict__ LC, float* __restrict__ SF, float* __restrict__ SI,
    float* __restrict__ next_mem, u16* __restrict__ AB) {
  const int chunk = blockIdx.x, h = blockIdx.y, b = blockIdx.z;
  const int bh = b * 8 + h;
  const int t0 = chunk * 32;
  const int tid = threadIdx.x;
  __shared__ __align__(16) float sk[2048], sq[2048], sv[2048];
  __shared__ float lsa[32], lsw[32];
  cg::grid_group grid = cg::this_grid();

  // ---- phase 0: gates + serial log-cumsum (one block per bh: chunk==0)
  if (chunk == 0) {
    float* ldec = sk;   // aliases: refilled in phase1 after grid sync
    float* lsvg = sq;
#pragma unroll
    for (int tt = 0; tt < 4; ++tt) {
      int t = tt * 256 + tid;
      size_t tok = (size_t)b * 1024 + t;
      float dl = G0[tok * 128 + h];
      float gwl = G0[tok * 128 + 8 + h];
      float gfl = G0[tok * 128 + 16 + h];
      float dd = dl > 20.f ? dl : log1pf(expf(dl));
      float sw = 1.f / (1.f + expf(-gwl));
      float gw = sw * sw;
      float sf = 1.f / (1.f + expf(-gfl));
      float gf = 1.f - sf * sf;
      float dec = fminf(fmaxf(dd * gf, 1e-6f), 0.999f);
      ldec[t] = dec;
      lsvg[t] = dd * gw;
      DEC[(size_t)bh * 1024 + t] = dec;
    }
    __syncthreads();
    if (tid < 64) {
      int lane = tid;
      size_t base = (size_t)bh * 1024 + lane * 16;
      float loc[16];
      float run = 0.f;
#pragma unroll
      for (int i = 0; i < 16; ++i) { run += logf(ldec[lane * 16 + i]); loc[i] = run; }
      float x = run;
#pragma unroll
      for (int o = 1; o < 64; o <<= 1) {
        float v = __shfl_up(x, o);
        if (lane >= o) x += v;
      }
      float excl = x - run;
#pragma unroll
      for (int i = 0; i < 16; ++i) {
        float L = excl + loc[i];
        LC[base + i] = L;
        float c = expf(L);
        WS[base + i] = (c / (c + 1e-8f)) * lsvg[lane * 16 + i];
      }
    }
  }
  grid.sync();

  // ---- phase 1: local scan of 32 steps, zero init; r kept in sv rows.
  {
    const u16* gk = KB + ((size_t)bh * 1024 + t0) * 64;
    const u16* gq = QB + ((size_t)bh * 1024 + t0) * 64;
    const u16* gv = VB + ((size_t)bh * 1024 + t0) * 64;
#pragma unroll
    for (int r = 0; r < 2; ++r) {
      int f = (r * 256 + tid) * 4;
      *(float4*)&sk[f] = b4_to_f4(*(const uint2*)(gk + f));
      *(float4*)&sq[f] = b4_to_f4(*(const uint2*)(gq + f));
      *(float4*)&sv[f] = b4_to_f4(*(const uint2*)(gv + f));
    }
    if (tid < 32) {
      size_t gi = (size_t)bh * 1024 + t0 + tid;
      lsa[tid] = DEC[gi];
      lsw[tid] = WS[gi];
    }
    __syncthreads();

    int i = tid >> 2, j0 = (tid & 3) * 16;
    float s[16];
#pragma unroll
    for (int z = 0; z < 16; ++z) s[z] = 0.f;

    for (int t = 0; t < 32; ++t) {
      float a = lsa[t], w = lsw[t];
      float wv = w * sv[t * 64 + i];
      float r = 0.f;
#pragma unroll
      for (int u4 = 0; u4 < 4; ++u4) {
        float4 kv = *(const float4*)&sk[t * 64 + j0 + u4 * 4];
        float4 qv = *(const float4*)&sq[t * 64 + j0 + u4 * 4];
        s[u4 * 4 + 0] = fmaf(a, s[u4 * 4 + 0], wv * kv.x); r = fmaf(s[u4 * 4 + 0], qv.x, r);
        s[u4 * 4 + 1] = fmaf(a, s[u4 * 4 + 1], wv * kv.y); r = fmaf(s[u4 * 4 + 1], qv.y, r);
        s[u4 * 4 + 2] = fmaf(a, s[u4 * 4 + 2], wv * kv.z); r = fmaf(s[u4 * 4 + 2], qv.z, r);
        s[u4 * 4 + 3] = fmaf(a, s[u4 * 4 + 3], wv * kv.w); r = fmaf(s[u4 * 4 + 3], qv.w, r);
      }
      r += __shfl_xor(r, 1);
      r += __shfl_xor(r, 2);
      // sv[t*64+i] was read by this wave earlier this iteration; safe to
      // overwrite with the local readout (same-wave program order).
      if ((tid & 3) == 0) sv[t * 64 + i] = r;
    }

    float* Sf = SF + ((size_t)bh * 32 + chunk) * 4096 + i * 64 + j0;
#pragma unroll
    for (int u4 = 0; u4 < 4; ++u4) {
      float4 v;
      v.x = s[u4 * 4 + 0]; v.y = s[u4 * 4 + 1]; v.z = s[u4 * 4 + 2]; v.w = s[u4 * 4 + 3];
      *(float4*)&Sf[u4 * 4] = v;
    }
  }
  grid.sync();

  // ---- phase 2: cross-chunk combine (blocks with chunk<16; e = chunk*256+tid).
  if (chunk < 16) {
    if (tid < 32) {
      float Lend = LC[(size_t)bh * 1024 + tid * 32 + 31];
      float Lpre = tid ? LC[(size_t)bh * 1024 + tid * 32 - 1] : 0.f;
      lsw[tid] = expf(Lend - Lpre);  // lsw dead after phase1 -> P factors
    }
    __syncthreads();
    int e = chunk * 256 + tid;
    const float* Sfb = SF + (size_t)bh * 32 * 4096 + e;
    float* Sib = SI + (size_t)bh * 32 * 4096 + e;
    float sf0[32];
#pragma unroll
    for (int c = 0; c < 32; ++c) sf0[c] = Sfb[(size_t)c * 4096];
    float s = 0.f;
#pragma unroll
    for (int c = 0; c < 32; ++c) {
      Sib[(size_t)c * 4096] = s;
      s = fmaf(lsw[c], s, sf0[c]);
    }
    next_mem[(size_t)bh * 4096 + e] = s;
  }
  grid.sync();

  // ---- phase 3: add inter-chunk contribution p_t*(Sinit @ q_t); readout.
  {
    if (tid < 32) lsa[tid] = LC[(size_t)bh * 1024 + t0 + tid];
    __syncthreads();
    float Lpre = chunk ? LC[(size_t)bh * 1024 + t0 - 1] : 0.f;
    int i = tid >> 2, j0 = (tid & 3) * 16;
    const float* Si = SI + ((size_t)bh * 32 + chunk) * 4096 + i * 64 + j0;
    float S[16];
#pragma unroll
    for (int u4 = 0; u4 < 4; ++u4) {
      float4 v = *(const float4*)&Si[u4 * 4];
      S[u4 * 4 + 0] = v.x; S[u4 * 4 + 1] = v.y; S[u4 * 4 + 2] = v.z; S[u4 * 4 + 3] = v.w;
    }

    for (int t = 0; t < 32; ++t) {
      float p = expf(lsa[t] - Lpre);
      float r = 0.f;
#pragma unroll
      for (int u4 = 0; u4 < 4; ++u4) {
        float4 qv = *(const float4*)&sq[t * 64 + j0 + u4 * 4];
        r = fmaf(S[u4 * 4 + 0], qv.x, r);
        r = fmaf(S[u4 * 4 + 1], qv.y, r);
        r = fmaf(S[u4 * 4 + 2], qv.z, r);
        r = fmaf(S[u4 * 4 + 3], qv.w, r);
      }
      r += __shfl_xor(r, 1);
      r += __shfl_xor(r, 2);
      if ((tid & 3) == 0) {
        size_t gi = ((size_t)(b * 1024 + t0 + t) * 8 + h) * 64 + i;
        AB[gi] = f2b(sv[t * 64 + i] + p * r);
      }
    }
  }
}

// ---------------------------------------------------------------------------
extern "C" void kernel_launch(void* const* d_in, const int* in_sizes, int n_in,
                              void* d_out, int out_size, void* d_ws, size_t ws_size,
                              hipStream_t stream) {
  const float* x = (const float*)d_in[0];
  const float* bmin = (const float*)d_in[1];
  const float* bmax = (const float*)d_in[2];
  const float* motif = (const float*)d_in[3];
  const float* Wk = (const float*)d_in[4];
  const float* bk = (const float*)d_in[5];
  const float* Wq = (const float*)d_in[6];
  const float* bq = (const float*)d_in[7];
  const float* Wv = (const float*)d_in[8];
  const float* bv = (const float*)d_in[9];
  const float* Wo = (const float*)d_in[10];
  const float* bo = (const float*)d_in[11];
  const float* Wd = (const float*)d_in[12];
  const float* bd = (const float*)d_in[13];
  const float* Wgw = (const float*)d_in[14];
  const float* bgw = (const float*)d_in[15];
  const float* Wgf = (const float*)d_in[16];
  const float* bgf = (const float*)d_in[17];
  const float* Wps = (const float*)d_in[18];
  const float* bps = (const float*)d_in[19];
  const float* ln1g = (const float*)d_in[20];
  const float* ln1b = (const float*)d_in[21];
  const float* ln2g = (const float*)d_in[22];
  const float* ln2b = (const float*)d_in[23];
  const float* W1 = (const float*)d_in[24];
  const float* b1 = (const float*)d_in[25];
  const float* W2 = (const float*)d_in[26];
  const float* b2 = (const float*)d_in[27];

  char* ws = (char*)d_ws;
  u16* WTQ = (u16*)(ws + 0);             // 1664x512 bf16 -> 1703936
  u16* WTO = (u16*)(ws + 1703936);       // -> 2228224
  u16* WT1 = (u16*)(ws + 2228224);       // -> 4325376
  u16* WT2 = (u16*)(ws + 4325376);       // -> 6422528
  u16* WTPS = (u16*)(ws + 6422528);      // -> 6946816
  float* BQV = (float*)(ws + 6946816);   // -> 6953472
  u16* XN = (u16*)(ws + 6953984);        // -> 9051136
  float* G0 = (float*)(ws + 9051136);    // 2048x128 f32 -> 10099712
  u16* KB = (u16*)(ws + 10099712);       // -> 12196864
  u16* QB = (u16*)(ws + 12196864);       // -> 14294016
  u16* VB = (u16*)(ws + 14294016);       // -> 16391168
  float* DEC = (float*)(ws + 16391168);  // -> 16456704
  float* LC = (float*)(ws + 16456704);   // -> 16522240
  float* WS = (float*)(ws + 16522240);   // -> 16587776 (WW*SVG premultiplied)
  float* SF = (float*)(ws + 20847616);   // 8MB -> 29236224
  float* SI = (float*)(ws + 29236224);   // 8MB -> 37624832
  u16* AB = (u16*)(ws + 37624832);       // 2MB -> 39721984
  float* X2 = (float*)(ws + 39721984);   // 4MB -> 43916288
  u16* HB = (u16*)(ws + 43916288);       // 2MB -> 46013440
  u16* MID = (u16*)(ws + 9051136);       // 8MB -> 17439744 (G0..WS dead at FFN1)
  u16* X3B = (u16*)(ws + 20847616);      // 2MB (SF dead at FFN2)

  float* out0 = (float*)d_out;
  float* out1 = out0 + 1048576;
  float* out2 = out0 + 1114112;
  float* out3 = out0 + 2162688;

  prep_weights<<<5440, 256, 0, stream>>>(Wk, Wq, Wv, Wo, Wps, W1, W2, Wd, Wgw, Wgf,
                                         bk, bq, bv, bd, bgw, bgf, x, ln1g, ln1b,
                                         WTQ, WTO, WTPS, WT1, WT2, BQV, XN);
  gemm2s<64, 5><<<dim3(26, 32), 256, 0, stream>>>(XN, WTQ, BQV, G0, nullptr, KB, QB, VB,
                                                  nullptr, nullptr, 2048, 1664, 512);
  {
    void* args[] = {(void*)&KB, (void*)&QB, (void*)&VB, (void*)&G0, (void*)&DEC,
                    (void*)&WS, (void*)&LC, (void*)&SF, (void*)&SI, (void*)&out1,
                    (void*)&AB};
    hipLaunchCooperativeKernel((const void*)scan_fused, dim3(32, 8, 2), dim3(256),
                               args, 0, stream);
  }

  gemm2s<32, 1><<<dim3(8, 64), 256, 0, stream>>>(AB, WTO, bo, X2, nullptr, nullptr,
                                                 nullptr, nullptr, x, motif, 2048, 512, 512);
  ln_f32<<<2048, 256, 0, stream>>>(X2, ln2g, ln2b, HB);
  gemm2s<64, 2><<<dim3(32, 32), 256, 0, stream>>>(HB, WT1, b1, nullptr, nullptr, MID,
                                                  nullptr, nullptr, nullptr, nullptr,
                                                  2048, 2048, 512);
  gemm2s<32, 3><<<dim3(8, 64), 256, 0, stream>>>(MID, WT2, b2, out0, nullptr, X3B,
                                                 nullptr, nullptr, X2, nullptr,
                                                 2048, 512, 2048);
  gemm2s<32, 4><<<dim3(8, 64), 256, 0, stream>>>(X3B, WTPS, bps, out2, out3, nullptr,
                                                 nullptr, nullptr, bmin, bmax,
                                                 2048, 512, 512);
}

// Round 3
// 236.443 us; speedup vs baseline: 1.9002x; 1.9002x over previous
//
#include <hip/hip_runtime.h>

// HoloGraphBlockV7 — round 12: revert R11's cooperative fusion (grid.sync cost
// ~180us idle — never again at this size). Keep R9 structure; improvements:
//  - gates_logcum writes WS = WW*SVG (one fewer stream in scan_phase1)
//  - scan_phase2+3 merged via prefix-recompute (bit-identical fma order);
//    SI buffer (8MB RT) and the serial phase2p chain eliminated; 10 dispatches.

typedef unsigned short u16;
typedef unsigned int u32;
typedef __attribute__((ext_vector_type(8))) short short8;
typedef __attribute__((ext_vector_type(4))) float floatx4;

__device__ __forceinline__ float b2f(u16 u) {
  u32 x = ((u32)u) << 16;
  return __uint_as_float(x);
}
__device__ __forceinline__ u16 f2b(float f) {
  u32 x = __float_as_uint(f);
  u32 r = (x + 0x7fffu + ((x >> 16) & 1u)) >> 16;
  return (u16)r;
}
__device__ __forceinline__ float4 b4_to_f4(uint2 u) {
  float4 r;
  r.x = __uint_as_float((u.x & 0xffffu) << 16);
  r.y = __uint_as_float(u.x & 0xffff0000u);
  r.z = __uint_as_float((u.y & 0xffffu) << 16);
  r.w = __uint_as_float(u.y & 0xffff0000u);
  return r;
}

__device__ __forceinline__ void stage16(const u16* g, u16* lds_wave_base) {
  __builtin_amdgcn_global_load_lds((const __attribute__((address_space(1))) void*)g,
                                   (__attribute__((address_space(3))) void*)lds_wave_base,
                                   16, 0, 0);
}

// Stage a ROWSx64 bf16 tile (64-wide k-block kb) into LDS [row][64] with
// chunk swizzle: LDS chunk slot m of row r holds global k-chunk m ^ (r&7).
template <int ROWS>
__device__ __forceinline__ void stage_tile64(const u16* __restrict__ G, int ldK, int kb,
                                             u16* lds, int tid) {
#pragma unroll
  for (int r = 0; r < ROWS / 32; ++r) {
    int slot = r * 256 + tid;
    int row = slot >> 3;
    int kwg = (slot & 7) ^ (row & 7);
    stage16(G + (size_t)row * ldK + kb * 64 + kwg * 8,
            lds + (size_t)(r * 256 + (tid >> 6) * 64) * 8);
  }
}

// ---------------------------------------------------------------------------
// LayerNorm of one 512-row; 256 threads.
__device__ __forceinline__ void ln_row(const float* __restrict__ xr,
                                       const float* __restrict__ g,
                                       const float* __restrict__ bt,
                                       u16* __restrict__ yr, int tid, float* red) {
  float x0 = xr[tid], x1 = xr[tid + 256];
  float s = x0 + x1, ss = x0 * x0 + x1 * x1;
#pragma unroll
  for (int o = 32; o > 0; o >>= 1) { s += __shfl_xor(s, o); ss += __shfl_xor(ss, o); }
  if ((tid & 63) == 0) { red[tid >> 6] = s; red[4 + (tid >> 6)] = ss; }
  __syncthreads();
  float ts = red[0] + red[1] + red[2] + red[3];
  float tss = red[4] + red[5] + red[6] + red[7];
  float mu = ts * (1.f / 512.f);
  float var = tss * (1.f / 512.f) - mu * mu;
  float rstd = 1.0f / sqrtf(var + 1e-5f);
  yr[tid] = f2b((x0 - mu) * rstd * g[tid] + bt[tid]);
  yr[tid + 256] = f2b((x1 - mu) * rstd * g[tid + 256] + bt[tid + 256]);
}

// ---------------------------------------------------------------------------
// Prep: weight transposes f32->bf16 (0..3327), gate/bias pack (3328..3391),
// LN1 rows (3392..5439).
__global__ __launch_bounds__(256) void prep_weights(
    const float* __restrict__ Wk, const float* __restrict__ Wq,
    const float* __restrict__ Wv, const float* __restrict__ Wo,
    const float* __restrict__ Wps, const float* __restrict__ W1,
    const float* __restrict__ W2, const float* __restrict__ Wd,
    const float* __restrict__ Wgw, const float* __restrict__ Wgf,
    const float* __restrict__ bk, const float* __restrict__ bq,
    const float* __restrict__ bv, const float* __restrict__ bd,
    const float* __restrict__ bgw, const float* __restrict__ bgf,
    const float* __restrict__ x, const float* __restrict__ ln1g,
    const float* __restrict__ ln1b,
    u16* __restrict__ WTQ, u16* __restrict__ WTO, u16* __restrict__ WTPS,
    u16* __restrict__ WT1, u16* __restrict__ WT2, float* __restrict__ BQV,
    u16* __restrict__ XN) {
  int bid = blockIdx.x, tid = threadIdx.x;
  __shared__ float tile[32][33];
  __shared__ float red[8];
  if (bid < 3328) {
    const float* src;
    u16* dst;
    int C, rel, tiles_x;
    if (bid < 256)       { src = Wk;  dst = WTQ;           C = 512;  rel = bid;        tiles_x = 16; }
    else if (bid < 512)  { src = Wq;  dst = WTQ + 262144;  C = 512;  rel = bid - 256;  tiles_x = 16; }
    else if (bid < 768)  { src = Wv;  dst = WTQ + 524288;  C = 512;  rel = bid - 512;  tiles_x = 16; }
    else if (bid < 1024) { src = Wo;  dst = WTO;           C = 512;  rel = bid - 768;  tiles_x = 16; }
    else if (bid < 1280) { src = Wps; dst = WTPS;          C = 512;  rel = bid - 1024; tiles_x = 16; }
    else if (bid < 2304) { src = W1;  dst = WT1;           C = 2048; rel = bid - 1280; tiles_x = 64; }
    else                 { src = W2;  dst = WT2;           C = 512;  rel = bid - 2304; tiles_x = 16; }
    int R = (bid >= 1280 && bid < 2304) ? 512 : (bid >= 2304 ? 2048 : 512);
    int c0 = (rel % tiles_x) * 32, r0 = (rel / tiles_x) * 32;
    int tx = tid & 31, ty = tid >> 5;
#pragma unroll
    for (int i = 0; i < 4; ++i)
      tile[ty + i * 8][tx] = src[(size_t)(r0 + ty + i * 8) * C + c0 + tx];
    __syncthreads();
#pragma unroll
    for (int i = 0; i < 4; ++i)
      dst[(size_t)(c0 + ty + i * 8) * R + r0 + tx] = f2b(tile[tx][ty + i * 8]);
  } else if (bid < 3392) {
    int idx = (bid - 3328) * 256 + tid;
    const int stride = 64 * 256;
    for (int i = idx; i < 128 * 512; i += stride) {
      int local = i >> 9, k = i & 511;
      float v = 0.f;
      if (local < 8) v = Wd[k * 8 + local];
      else if (local < 16) v = Wgw[k * 8 + (local - 8)];
      else if (local < 24) v = Wgf[k * 8 + (local - 16)];
      WTQ[(size_t)(1536 + local) * 512 + k] = f2b(v);
    }
    for (int i = idx; i < 1664; i += stride) {
      float v = 0.f;
      if (i < 512) v = bk[i];
      else if (i < 1024) v = bq[i - 512];
      else if (i < 1536) v = bv[i - 1024];
      else if (i < 1544) v = bd[i - 1536];
      else if (i < 1552) v = bgw[i - 1544];
      else if (i < 1560) v = bgf[i - 1552];
      BQV[i] = v;
    }
  } else {
    int row = bid - 3392;
    ln_row(x + (size_t)row * 512, ln1g, ln1b, XN + (size_t)row * 512, tid, red);
  }
}

// Standalone LN2.
__global__ __launch_bounds__(256) void ln_f32(const float* __restrict__ X,
                                              const float* __restrict__ g,
                                              const float* __restrict__ bt,
                                              u16* __restrict__ Y) {
  __shared__ float red[8];
  ln_row(X + (size_t)blockIdx.x * 512, g, bt, Y + (size_t)blockIdx.x * 512,
         threadIdx.x, red);
}

// ---------------------------------------------------------------------------
// BMx64-tile, BK=64, 2-stage LDS GEMM. 256 threads = 2x2 waves.
// BM=64: 4 blocks/CU; BM=32: 6 blocks/CU.
// EPI 1: outf = aux0+v+0.1*aux1
// EPI 2: outb = bf16(gelu(v))
// EPI 3: w = aux0+v; outf = w; outb = bf16(w)
// EPI 4: outf = aux0+v; outf2 = aux1+v
// EPI 5 (QKV, N=1664): n-tile sections: [0,512) l2norm->outb(KB);
//   [512,1024) l2norm->outb2(QB); [1024,1536) tanh->outb3(VB);
//   [1536,1664) raw f32 -> outf(G0, 2048x128).
template <int BM, int EPI>
__global__ __launch_bounds__(256, (BM == 128 ? 3 : BM == 64 ? 4 : 6)) void gemm2s(
    const u16* __restrict__ A, const u16* __restrict__ BT, const float* __restrict__ bias,
    float* __restrict__ outf, float* __restrict__ outf2, u16* __restrict__ outb,
    u16* __restrict__ outb2, u16* __restrict__ outb3,
    const float* __restrict__ aux0, const float* __restrict__ aux1, int M, int N, int K) {
  constexpr int MT = BM / 32;
  constexpr int S = BM / 32 + 2;  // DMA insts per thread per k-tile
  __shared__ __align__(16) u16 As[2][BM * 64];
  __shared__ __align__(16) u16 Bs[2][64 * 64];
  __shared__ float ssb[2][BM];
  const int tid = threadIdx.x;
  const int lane = tid & 63, wave = tid >> 6;
  const int wm = wave >> 1, wn = wave & 1;
  const int m0 = blockIdx.y * BM, n0 = blockIdx.x * 64;
  floatx4 acc[MT][2] = {};
  const int fr = lane & 15, kq = lane >> 4;
  const int nk = K >> 6;
  const u16* Ab = A + (size_t)m0 * K;
  const u16* Bb = BT + (size_t)n0 * K;

  stage_tile64<BM>(Ab, K, 0, As[0], tid);
  stage_tile64<64>(Bb, K, 0, Bs[0], tid);

  for (int kb = 0; kb < nk; ++kb) {
    const int cur = kb & 1;
    if (kb + 1 < nk) {
      stage_tile64<BM>(Ab, K, kb + 1, As[cur ^ 1], tid);
      stage_tile64<64>(Bb, K, kb + 1, Bs[cur ^ 1], tid);
      if constexpr (S == 6) asm volatile("s_waitcnt vmcnt(6)" ::: "memory");
      else if constexpr (S == 4) asm volatile("s_waitcnt vmcnt(4)" ::: "memory");
      else asm volatile("s_waitcnt vmcnt(3)" ::: "memory");
    } else {
      asm volatile("s_waitcnt vmcnt(0)" ::: "memory");
    }
    asm volatile("s_barrier" ::: "memory");

#pragma unroll
    for (int sub = 0; sub < 2; ++sub) {
      short8 af[MT], bf[2];
#pragma unroll
      for (int mt = 0; mt < MT; ++mt) {
        int row = wm * (BM / 2) + mt * 16 + fr;
        int c = sub * 4 + kq;
        af[mt] = *(const short8*)&As[cur][row * 64 + ((c ^ (row & 7)) << 3)];
      }
#pragma unroll
      for (int nt = 0; nt < 2; ++nt) {
        int row = wn * 32 + nt * 16 + fr;
        int c = sub * 4 + kq;
        bf[nt] = *(const short8*)&Bs[cur][row * 64 + ((c ^ (row & 7)) << 3)];
      }
#pragma unroll
      for (int mt = 0; mt < MT; ++mt)
#pragma unroll
        for (int nt = 0; nt < 2; ++nt)
          acc[mt][nt] =
              __builtin_amdgcn_mfma_f32_16x16x32_bf16(af[mt], bf[nt], acc[mt][nt], 0, 0, 0);
    }
    asm volatile("s_waitcnt lgkmcnt(0)" ::: "memory");
    asm volatile("s_barrier" ::: "memory");
  }

  const int col = lane & 15;
  const int rbase = (lane >> 4) * 4;

  // v (acc + bias), per (mt, nt, r)
  float vv[MT][2][4];
#pragma unroll
  for (int nt = 0; nt < 2; ++nt) {
    int gc = n0 + wn * 32 + nt * 16 + col;
    float bvv = bias[gc];
#pragma unroll
    for (int mt = 0; mt < MT; ++mt)
#pragma unroll
      for (int r = 0; r < 4; ++r) vv[mt][nt][r] = acc[mt][nt][r] + bvv;
  }

  if constexpr (EPI == 5) {
    const int sec = n0 >> 9;              // 0 K, 1 Q, 2 V, 3 gates
    const int h = (n0 & 511) >> 6;        // head (BN=64 == head size)
    if (sec == 3) {
#pragma unroll
      for (int nt = 0; nt < 2; ++nt) {
        int gcl = (n0 - 1536) + wn * 32 + nt * 16 + col;
#pragma unroll
        for (int mt = 0; mt < MT; ++mt) {
          int gr = m0 + wm * (BM / 2) + mt * 16 + rbase;
#pragma unroll
          for (int r = 0; r < 4; ++r)
            outf[(size_t)(gr + r) * 128 + gcl] = vv[mt][nt][r];
        }
      }
    } else if (sec == 2) {
#pragma unroll
      for (int nt = 0; nt < 2; ++nt) {
        int d = wn * 32 + nt * 16 + col;
#pragma unroll
        for (int mt = 0; mt < MT; ++mt) {
          int gr = m0 + wm * (BM / 2) + mt * 16 + rbase;
#pragma unroll
          for (int r = 0; r < 4; ++r) {
            int tok = gr + r;
            int bh = (tok >> 10) * 8 + h;
            outb3[((size_t)bh * 1024 + (tok & 1023)) * 64 + d] = f2b(tanhf(vv[mt][nt][r]));
          }
        }
      }
    } else {
      // l2norm over the head's 64 cols: wave-local 32-col sum + LDS exchange.
#pragma unroll
      for (int mt = 0; mt < MT; ++mt) {
#pragma unroll
        for (int r = 0; r < 4; ++r) {
          float ss = vv[mt][0][r] * vv[mt][0][r] + vv[mt][1][r] * vv[mt][1][r];
          ss += __shfl_xor(ss, 1);
          ss += __shfl_xor(ss, 2);
          ss += __shfl_xor(ss, 4);
          ss += __shfl_xor(ss, 8);
          if ((lane & 15) == 0)
            ssb[wn][wm * (BM / 2) + mt * 16 + rbase + r] = ss;
        }
      }
      __syncthreads();
      u16* dst = (sec == 0) ? outb : outb2;
#pragma unroll
      for (int mt = 0; mt < MT; ++mt) {
#pragma unroll
        for (int r = 0; r < 4; ++r) {
          int br = wm * (BM / 2) + mt * 16 + rbase + r;
          float tot = ssb[0][br] + ssb[1][br];
          float rs = 1.0f / fmaxf(sqrtf(tot), 1e-12f);
          int tok = m0 + br;
          int bh = (tok >> 10) * 8 + h;
          size_t base = ((size_t)bh * 1024 + (tok & 1023)) * 64;
#pragma unroll
          for (int nt = 0; nt < 2; ++nt) {
            int d = wn * 32 + nt * 16 + col;
            dst[base + d] = f2b(vv[mt][nt][r] * rs);
          }
        }
      }
    }
  } else {
#pragma unroll
    for (int nt = 0; nt < 2; ++nt) {
      int gc = n0 + wn * 32 + nt * 16 + col;
#pragma unroll
      for (int mt = 0; mt < MT; ++mt) {
        int gr = m0 + wm * (BM / 2) + mt * 16 + rbase;
#pragma unroll
        for (int r = 0; r < 4; ++r) {
          size_t idx = (size_t)(gr + r) * N + gc;
          float v = vv[mt][nt][r];
          if constexpr (EPI == 1) {
            outf[idx] = aux0[idx] + v + 0.1f * aux1[idx];
          } else if constexpr (EPI == 2) {
            outb[idx] = f2b(0.5f * v * (1.f + erff(v * 0.70710678118654752f)));
          } else if constexpr (EPI == 3) {
            float w = aux0[idx] + v;
            outf[idx] = w;
            outb[idx] = f2b(w);
          } else if constexpr (EPI == 4) {
            outf[idx] = aux0[idx] + v;
            outf2[idx] = aux1[idx] + v;
          }
        }
      }
    }
  }
}

// ---------------------------------------------------------------------------
// Gates (softplus/sigmoid) + DEC + serial log-cumsum; WS = WW*SVG fused.
// grid = 16 (b,h); 256 threads.
__global__ __launch_bounds__(256) void gates_logcum(
    const float* __restrict__ G0, float* __restrict__ DEC, float* __restrict__ WS,
    float* __restrict__ LC) {
  int bh = blockIdx.x;
  int b = bh >> 3, h = bh & 7;
  int tid = threadIdx.x;
  __shared__ float ldec[1024];
  __shared__ float lsvg[1024];
#pragma unroll
  for (int tt = 0; tt < 4; ++tt) {
    int t = tt * 256 + tid;
    size_t tok = (size_t)b * 1024 + t;
    float dl = G0[tok * 128 + h];
    float gwl = G0[tok * 128 + 8 + h];
    float gfl = G0[tok * 128 + 16 + h];
    float dd = dl > 20.f ? dl : log1pf(expf(dl));
    float sw = 1.f / (1.f + expf(-gwl));
    float gw = sw * sw;
    float sf = 1.f / (1.f + expf(-gfl));
    float gf = 1.f - sf * sf;
    float dec = fminf(fmaxf(dd * gf, 1e-6f), 0.999f);
    ldec[t] = dec;
    lsvg[t] = dd * gw;
    DEC[(size_t)bh * 1024 + t] = dec;
  }
  __syncthreads();
  if (tid < 64) {
    int lane = tid;
    size_t base = (size_t)bh * 1024 + lane * 16;
    float loc[16];
    float run = 0.f;
#pragma unroll
    for (int i = 0; i < 16; ++i) { run += logf(ldec[lane * 16 + i]); loc[i] = run; }
    float x = run;
#pragma unroll
    for (int o = 1; o < 64; o <<= 1) {
      float v = __shfl_up(x, o);
      if (lane >= o) x += v;
    }
    float excl = x - run;
#pragma unroll
    for (int i = 0; i < 16; ++i) {
      float L = excl + loc[i];
      LC[base + i] = L;
      float c = expf(L);
      WS[base + i] = (c / (c + 1e-8f)) * lsvg[lane * 16 + i];
    }
  }
}

// ---------------------------------------------------------------------------
// Scan phase 1: per (chunk,h,b) local scan of 32 steps, zero init.
// Per-step weight WS = WW*SVG premultiplied upstream.
__global__ __launch_bounds__(256, 2) void scan_phase1(
    const u16* __restrict__ KB, const u16* __restrict__ QB, const u16* __restrict__ VB,
    const float* __restrict__ DEC, const float* __restrict__ WS,
    float* __restrict__ RP, float* __restrict__ SF) {
  int chunk = blockIdx.x, h = blockIdx.y, b = blockIdx.z;
  int bh = b * 8 + h;
  int t0 = chunk * 32;
  __shared__ __align__(16) float sk[2048], sq[2048], sv[2048];
  __shared__ float lsa[32], lsw[32];
  int tid = threadIdx.x;

  const u16* gk = KB + ((size_t)bh * 1024 + t0) * 64;
  const u16* gq = QB + ((size_t)bh * 1024 + t0) * 64;
  const u16* gv = VB + ((size_t)bh * 1024 + t0) * 64;
#pragma unroll
  for (int r = 0; r < 2; ++r) {
    int f = (r * 256 + tid) * 4;
    *(float4*)&sk[f] = b4_to_f4(*(const uint2*)(gk + f));
    *(float4*)&sq[f] = b4_to_f4(*(const uint2*)(gq + f));
    *(float4*)&sv[f] = b4_to_f4(*(const uint2*)(gv + f));
  }
  if (tid < 32) {
    size_t gi = (size_t)bh * 1024 + t0 + tid;
    lsa[tid] = DEC[gi];
    lsw[tid] = WS[gi];
  }
  __syncthreads();

  int i = tid >> 2, j0 = (tid & 3) * 16;
  float s[16];
#pragma unroll
  for (int z = 0; z < 16; ++z) s[z] = 0.f;

  for (int t = 0; t < 32; ++t) {
    float a = lsa[t], w = lsw[t];
    float wv = w * sv[t * 64 + i];
    float r = 0.f;
#pragma unroll
    for (int u4 = 0; u4 < 4; ++u4) {
      float4 kv = *(const float4*)&sk[t * 64 + j0 + u4 * 4];
      float4 qv = *(const float4*)&sq[t * 64 + j0 + u4 * 4];
      s[u4 * 4 + 0] = fmaf(a, s[u4 * 4 + 0], wv * kv.x); r = fmaf(s[u4 * 4 + 0], qv.x, r);
      s[u4 * 4 + 1] = fmaf(a, s[u4 * 4 + 1], wv * kv.y); r = fmaf(s[u4 * 4 + 1], qv.y, r);
      s[u4 * 4 + 2] = fmaf(a, s[u4 * 4 + 2], wv * kv.z); r = fmaf(s[u4 * 4 + 2], qv.z, r);
      s[u4 * 4 + 3] = fmaf(a, s[u4 * 4 + 3], wv * kv.w); r = fmaf(s[u4 * 4 + 3], qv.w, r);
    }
    r += __shfl_xor(r, 1);
    r += __shfl_xor(r, 2);
    if ((tid & 3) == 0)
      RP[((size_t)(b * 1024 + t0 + t) * 8 + h) * 64 + i] = r;
  }

  float* Sf = SF + ((size_t)bh * 32 + chunk) * 4096 + i * 64 + j0;
#pragma unroll
  for (int u4 = 0; u4 < 4; ++u4) {
    float4 v;
    v.x = s[u4 * 4 + 0]; v.y = s[u4 * 4 + 1]; v.z = s[u4 * 4 + 2]; v.w = s[u4 * 4 + 3];
    *(float4*)&Sf[u4 * 4] = v;
  }
}

// ---------------------------------------------------------------------------
// Scan phase 2+3 merged: each (chunk,h,b) block recomputes its SI prefix
// S = scan over c<chunk of s=fmaf(P_c,s,SF_c)  (bit-identical order to the
// old phase2), then adds p_t*(S @ q_t) to the local readout. chunk==31
// blocks additionally emit next_mem. SI buffer + phase2 kernel eliminated.
__global__ __launch_bounds__(256, 2) void scan_phase23(
    const u16* __restrict__ QB, const float* __restrict__ SF, const float* __restrict__ LC,
    const float* __restrict__ RP, float* __restrict__ next_mem, u16* __restrict__ AB) {
  int chunk = blockIdx.x, h = blockIdx.y, b = blockIdx.z;
  int bh = b * 8 + h;
  int t0 = chunk * 32;
  __shared__ __align__(16) float sq[2048];
  __shared__ float sL[32], sP[32];
  int tid = threadIdx.x;

  const u16* gq = QB + ((size_t)bh * 1024 + t0) * 64;
#pragma unroll
  for (int r = 0; r < 2; ++r) {
    int f = (r * 256 + tid) * 4;
    *(float4*)&sq[f] = b4_to_f4(*(const uint2*)(gq + f));
  }
  if (tid < 32) {
    sL[tid] = LC[(size_t)bh * 1024 + t0 + tid];
    float Lend = LC[(size_t)bh * 1024 + tid * 32 + 31];
    float Lpre = tid ? LC[(size_t)bh * 1024 + tid * 32 - 1] : 0.f;
    sP[tid] = expf(Lend - Lpre);
  }
  __syncthreads();

  int i = tid >> 2, j0 = (tid & 3) * 16;
  const float* Sfb = SF + (size_t)bh * 32 * 4096 + i * 64 + j0;

  // Prefix over chunks c < chunk (16 independent fma chains/thread).
  float S[16];
#pragma unroll
  for (int z = 0; z < 16; ++z) S[z] = 0.f;
  for (int c = 0; c < chunk; ++c) {
    float P = sP[c];
    const float* row = Sfb + (size_t)c * 4096;
    float4 f0 = *(const float4*)&row[0];
    float4 f1 = *(const float4*)&row[4];
    float4 f2 = *(const float4*)&row[8];
    float4 f3 = *(const float4*)&row[12];
    S[0] = fmaf(P, S[0], f0.x);  S[1] = fmaf(P, S[1], f0.y);
    S[2] = fmaf(P, S[2], f0.z);  S[3] = fmaf(P, S[3], f0.w);
    S[4] = fmaf(P, S[4], f1.x);  S[5] = fmaf(P, S[5], f1.y);
    S[6] = fmaf(P, S[6], f1.z);  S[7] = fmaf(P, S[7], f1.w);
    S[8] = fmaf(P, S[8], f2.x);  S[9] = fmaf(P, S[9], f2.y);
    S[10] = fmaf(P, S[10], f2.z); S[11] = fmaf(P, S[11], f2.w);
    S[12] = fmaf(P, S[12], f3.x); S[13] = fmaf(P, S[13], f3.y);
    S[14] = fmaf(P, S[14], f3.z); S[15] = fmaf(P, S[15], f3.w);
  }

  if (chunk == 31) {
    // One more step (c=31) produces the final state -> next_mem.
    float P = sP[31];
    const float* row = Sfb + (size_t)31 * 4096;
    float* nm = next_mem + (size_t)bh * 4096 + i * 64 + j0;
#pragma unroll
    for (int u4 = 0; u4 < 4; ++u4) {
      float4 f = *(const float4*)&row[u4 * 4];
      float4 o;
      o.x = fmaf(P, S[u4 * 4 + 0], f.x);
      o.y = fmaf(P, S[u4 * 4 + 1], f.y);
      o.z = fmaf(P, S[u4 * 4 + 2], f.z);
      o.w = fmaf(P, S[u4 * 4 + 3], f.w);
      *(float4*)&nm[u4 * 4] = o;
    }
  }

  float Lpre = chunk ? LC[(size_t)bh * 1024 + t0 - 1] : 0.f;
  for (int t = 0; t < 32; ++t) {
    float p = expf(sL[t] - Lpre);
    float r = 0.f;
#pragma unroll
    for (int u4 = 0; u4 < 4; ++u4) {
      float4 qv = *(const float4*)&sq[t * 64 + j0 + u4 * 4];
      r = fmaf(S[u4 * 4 + 0], qv.x, r);
      r = fmaf(S[u4 * 4 + 1], qv.y, r);
      r = fmaf(S[u4 * 4 + 2], qv.z, r);
      r = fmaf(S[u4 * 4 + 3], qv.w, r);
    }
    r += __shfl_xor(r, 1);
    r += __shfl_xor(r, 2);
    if ((tid & 3) == 0) {
      size_t gi = ((size_t)(b * 1024 + t0 + t) * 8 + h) * 64 + i;
      AB[gi] = f2b(RP[gi] + p * r);
    }
  }
}

// ---------------------------------------------------------------------------
extern "C" void kernel_launch(void* const* d_in, const int* in_sizes, int n_in,
                              void* d_out, int out_size, void* d_ws, size_t ws_size,
                              hipStream_t stream) {
  const float* x = (const float*)d_in[0];
  const float* bmin = (const float*)d_in[1];
  const float* bmax = (const float*)d_in[2];
  const float* motif = (const float*)d_in[3];
  const float* Wk = (const float*)d_in[4];
  const float* bk = (const float*)d_in[5];
  const float* Wq = (const float*)d_in[6];
  const float* bq = (const float*)d_in[7];
  const float* Wv = (const float*)d_in[8];
  const float* bv = (const float*)d_in[9];
  const float* Wo = (const float*)d_in[10];
  const float* bo = (const float*)d_in[11];
  const float* Wd = (const float*)d_in[12];
  const float* bd = (const float*)d_in[13];
  const float* Wgw = (const float*)d_in[14];
  const float* bgw = (const float*)d_in[15];
  const float* Wgf = (const float*)d_in[16];
  const float* bgf = (const float*)d_in[17];
  const float* Wps = (const float*)d_in[18];
  const float* bps = (const float*)d_in[19];
  const float* ln1g = (const float*)d_in[20];
  const float* ln1b = (const float*)d_in[21];
  const float* ln2g = (const float*)d_in[22];
  const float* ln2b = (const float*)d_in[23];
  const float* W1 = (const float*)d_in[24];
  const float* b1 = (const float*)d_in[25];
  const float* W2 = (const float*)d_in[26];
  const float* b2 = (const float*)d_in[27];

  char* ws = (char*)d_ws;
  u16* WTQ = (u16*)(ws + 0);             // 1664x512 bf16 -> 1703936
  u16* WTO = (u16*)(ws + 1703936);       // -> 2228224
  u16* WT1 = (u16*)(ws + 2228224);       // -> 4325376
  u16* WT2 = (u16*)(ws + 4325376);       // -> 6422528
  u16* WTPS = (u16*)(ws + 6422528);      // -> 6946816
  float* BQV = (float*)(ws + 6946816);   // -> 6953472
  u16* XN = (u16*)(ws + 6953984);        // -> 9051136
  float* G0 = (float*)(ws + 9051136);    // 2048x128 f32 -> 10099712
  u16* KB = (u16*)(ws + 10099712);       // -> 12196864
  u16* QB = (u16*)(ws + 12196864);       // -> 14294016
  u16* VB = (u16*)(ws + 14294016);       // -> 16391168
  float* DEC = (float*)(ws + 16391168);  // -> 16456704
  float* LC = (float*)(ws + 16456704);   // -> 16522240
  float* WS = (float*)(ws + 16522240);   // -> 16587776 (WW*SVG premultiplied)
  float* RP = (float*)(ws + 16653312);   // 4MB -> 20847616
  float* SF = (float*)(ws + 20847616);   // 8MB -> 29236224
  u16* AB = (u16*)(ws + 37624832);       // 2MB -> 39721984
  float* X2 = (float*)(ws + 39721984);   // 4MB -> 43916288
  u16* HB = (u16*)(ws + 43916288);       // 2MB -> 46013440
  u16* MID = (u16*)(ws + 9051136);       // 8MB -> 17439744 (G0..WS,RP dead at FFN1)
  u16* X3B = (u16*)(ws + 29236224);      // 2MB (dead region at FFN2)

  float* out0 = (float*)d_out;
  float* out1 = out0 + 1048576;
  float* out2 = out0 + 1114112;
  float* out3 = out0 + 2162688;

  prep_weights<<<5440, 256, 0, stream>>>(Wk, Wq, Wv, Wo, Wps, W1, W2, Wd, Wgw, Wgf,
                                         bk, bq, bv, bd, bgw, bgf, x, ln1g, ln1b,
                                         WTQ, WTO, WTPS, WT1, WT2, BQV, XN);
  gemm2s<64, 5><<<dim3(26, 32), 256, 0, stream>>>(XN, WTQ, BQV, G0, nullptr, KB, QB, VB,
                                                  nullptr, nullptr, 2048, 1664, 512);
  gates_logcum<<<16, 256, 0, stream>>>(G0, DEC, WS, LC);
  scan_phase1<<<dim3(32, 8, 2), 256, 0, stream>>>(KB, QB, VB, DEC, WS, RP, SF);
  scan_phase23<<<dim3(32, 8, 2), 256, 0, stream>>>(QB, SF, LC, RP, out1, AB);

  gemm2s<32, 1><<<dim3(8, 64), 256, 0, stream>>>(AB, WTO, bo, X2, nullptr, nullptr,
                                                 nullptr, nullptr, x, motif, 2048, 512, 512);
  ln_f32<<<2048, 256, 0, stream>>>(X2, ln2g, ln2b, HB);
  gemm2s<64, 2><<<dim3(32, 32), 256, 0, stream>>>(HB, WT1, b1, nullptr, nullptr, MID,
                                                  nullptr, nullptr, nullptr, nullptr,
                                                  2048, 2048, 512);
  gemm2s<32, 3><<<dim3(8, 64), 256, 0, stream>>>(MID, WT2, b2, out0, nullptr, X3B,
                                                 nullptr, nullptr, X2, nullptr,
                                                 2048, 512, 2048);
  gemm2s<32, 4><<<dim3(8, 64), 256, 0, stream>>>(X3B, WTPS, bps, out2, out3, nullptr,
                                                 nullptr, nullptr, bmin, bmax,
                                                 2048, 512, 512);
}